// Round 12
// baseline (1102.742 us; speedup 1.0000x reference)
//
#include <hip/hip_runtime.h>

#define D 64
#define D4 16   // D/4 float4 per row
#define PITCH 68  // LDS tile pitch: 16B-aligned b128 rows, <=2-way banks

typedef float4 f4;

__device__ __forceinline__ float leaky02(float x) { return (x >= 0.f) ? x : 0.2f * x; }

__device__ __forceinline__ f4 f4add(f4 a, f4 b) {
    return make_float4(a.x + b.x, a.y + b.y, a.z + b.z, a.w + b.w);
}
__device__ __forceinline__ f4 f4fma(float s, f4 v, f4 a) {
    return make_float4(fmaf(s, v.x, a.x), fmaf(s, v.y, a.y), fmaf(s, v.z, a.z), fmaf(s, v.w, a.w));
}
__device__ __forceinline__ f4 f4scale(f4 a, float s) {
    return make_float4(a.x * s, a.y * s, a.z * s, a.w * s);
}

// ---------------- CSR build ----------------

__global__ __launch_bounds__(256) void hist_kernel(const int* __restrict__ dst,
                                                   int* __restrict__ cnt, int ne) {
    int e = blockIdx.x * blockDim.x + threadIdx.x;
    if (e < ne) atomicAdd(&cnt[dst[e]], 1);
}

#define SCAN_BS 256
__global__ __launch_bounds__(SCAN_BS) void scan1_kernel(const int* __restrict__ cnt,
                                                        int* __restrict__ incl,
                                                        int* __restrict__ partials, int n) {
    __shared__ int sm[SCAN_BS];
    int g = blockIdx.x * SCAN_BS + threadIdx.x;
    int v = (g < n) ? cnt[g] : 0;
    sm[threadIdx.x] = v;
    __syncthreads();
    for (int off = 1; off < SCAN_BS; off <<= 1) {
        int t = (threadIdx.x >= off) ? sm[threadIdx.x - off] : 0;
        __syncthreads();
        sm[threadIdx.x] += t;
        __syncthreads();
    }
    if (g < n) incl[g] = sm[threadIdx.x];
    if (threadIdx.x == SCAN_BS - 1) partials[blockIdx.x] = sm[threadIdx.x];
}

__global__ __launch_bounds__(1024) void scan2_kernel(int* __restrict__ partials, int nb) {
    __shared__ int sm[1024];
    int t = threadIdx.x;
    int v = (t < nb) ? partials[t] : 0;
    sm[t] = v;
    __syncthreads();
    for (int off = 1; off < 1024; off <<= 1) {
        int x = (t >= off) ? sm[t - off] : 0;
        __syncthreads();
        sm[t] += x;
        __syncthreads();
    }
    if (t < nb) partials[t] = sm[t] - v;   // exclusive
}

__global__ __launch_bounds__(SCAN_BS) void scan3_kernel(const int* __restrict__ cnt,
                                                        const int* __restrict__ incl,
                                                        const int* __restrict__ partials,
                                                        int* __restrict__ rowptr,
                                                        int* __restrict__ cursor, int n, int ne) {
    int g = blockIdx.x * SCAN_BS + threadIdx.x;
    if (g < n) {
        int rp = incl[g] - cnt[g] + partials[blockIdx.x];
        rowptr[g] = rp;
        cursor[g] = rp;
    }
    if (g == 0) rowptr[n] = ne;
}

__global__ __launch_bounds__(256) void fill_kernel(const int* __restrict__ src,
                                                   const int* __restrict__ dst,
                                                   int* __restrict__ cursor,
                                                   int* __restrict__ col, int ne) {
    int e = blockIdx.x * blockDim.x + threadIdx.x;
    if (e < ne) {
        int pos = atomicAdd(&cursor[dst[e]], 1);
        __builtin_nontemporal_store(src[e], &col[pos]);   // bypass L2 alloc for scattered 4B
    }
}

// ---------------- LDS staging: T[k][row] transposed from row-major G[rows][64] ----------------

__device__ __forceinline__ void stageT(float* __restrict__ T, const f4* __restrict__ G4,
                                       int t, int valid_rows) {
    int row = t >> 2;
    int kq0 = t & 3;
#pragma unroll
    for (int c = 0; c < 4; c++) {
        int kq = kq0 + 4 * c;
        f4 r = make_float4(0.f, 0.f, 0.f, 0.f);
        if (row < valid_rows) r = G4[(size_t)row * 16 + kq];
        int k0 = kq * 4;
        T[(k0 + 0) * PITCH + row] = r.x;
        T[(k0 + 1) * PITCH + row] = r.y;
        T[(k0 + 2) * PITCH + row] = r.z;
        T[(k0 + 3) * PITCH + row] = r.w;
    }
}

// 4x4 register-tile inner product over K: acc[i][j] += At[k][4r+i]*Wt[k][4c+j]
#define TILE_MM(At, Wt, acc, r, c, KDIM)                                      \
    for (int k = 0; k < KDIM; k++) {                                          \
        f4 a = *(const f4*)&(At)[k * PITCH + (r) * 4];                        \
        f4 w = *(const f4*)&(Wt)[k * PITCH + (c) * 4];                        \
        acc[0][0] = fmaf(a.x, w.x, acc[0][0]);                                \
        acc[0][1] = fmaf(a.x, w.y, acc[0][1]);                                \
        acc[0][2] = fmaf(a.x, w.z, acc[0][2]);                                \
        acc[0][3] = fmaf(a.x, w.w, acc[0][3]);                                \
        acc[1][0] = fmaf(a.y, w.x, acc[1][0]);                                \
        acc[1][1] = fmaf(a.y, w.y, acc[1][1]);                                \
        acc[1][2] = fmaf(a.y, w.z, acc[1][2]);                                \
        acc[1][3] = fmaf(a.y, w.w, acc[1][3]);                                \
        acc[2][0] = fmaf(a.z, w.x, acc[2][0]);                                \
        acc[2][1] = fmaf(a.z, w.y, acc[2][1]);                                \
        acc[2][2] = fmaf(a.z, w.z, acc[2][2]);                                \
        acc[2][3] = fmaf(a.z, w.w, acc[2][3]);                                \
        acc[3][0] = fmaf(a.w, w.x, acc[3][0]);                                \
        acc[3][1] = fmaf(a.w, w.y, acc[3][1]);                                \
        acc[3][2] = fmaf(a.w, w.z, acc[3][2]);                                \
        acc[3][3] = fmaf(a.w, w.w, acc[3][3]);                                \
    }

// ---------------- SAGE gather: M[i] = mean_{j in N(i)} h[j]  (reference order) ----------------
// One wave per node; 4 edge-groups x 16 feature-lanes; 16 edges in flight.

__global__ __launch_bounds__(256) void sage_gather(const f4* __restrict__ H,
                                                   const int* __restrict__ rowptr,
                                                   const int* __restrict__ col,
                                                   f4* __restrict__ M, int n) {
    int lane = threadIdx.x & 63;
    int eg = lane >> 4, l16 = lane & 15;
    int wave = (blockIdx.x * 256 + threadIdx.x) >> 6;
    int nw = (gridDim.x * 256) >> 6;
    for (int node = wave; node < n; node += nw) {
        int start = rowptr[node], end = rowptr[node + 1];
        int len = end - start;
        f4 a0 = {0, 0, 0, 0}, a1 = {0, 0, 0, 0}, a2 = {0, 0, 0, 0}, a3 = {0, 0, 0, 0};
        int main16 = len & ~15;
        int o = 0;
        for (; o < main16; o += 16) {
            int i0 = start + o + eg;
            int s0 = __builtin_nontemporal_load(&col[i0]);
            int s1 = __builtin_nontemporal_load(&col[i0 + 4]);
            int s2 = __builtin_nontemporal_load(&col[i0 + 8]);
            int s3 = __builtin_nontemporal_load(&col[i0 + 12]);
            f4 r0 = H[(size_t)s0 * D4 + l16];
            f4 r1 = H[(size_t)s1 * D4 + l16];
            f4 r2 = H[(size_t)s2 * D4 + l16];
            f4 r3 = H[(size_t)s3 * D4 + l16];
            a0 = f4add(a0, r0); a1 = f4add(a1, r1);
            a2 = f4add(a2, r2); a3 = f4add(a3, r3);
        }
        int rem = len - o;
        if (rem > 0) {
            int i0 = start + o;
            if (eg < rem)      a0 = f4add(a0, H[(size_t)col[i0 + eg] * D4 + l16]);
            if (eg + 4 < rem)  a1 = f4add(a1, H[(size_t)col[i0 + 4 + eg] * D4 + l16]);
            if (eg + 8 < rem)  a2 = f4add(a2, H[(size_t)col[i0 + 8 + eg] * D4 + l16]);
            if (eg + 12 < rem) a3 = f4add(a3, H[(size_t)col[i0 + 12 + eg] * D4 + l16]);
        }
        f4 a = f4add(f4add(a0, a1), f4add(a2, a3));
        a.x += __shfl_xor(a.x, 16); a.y += __shfl_xor(a.y, 16);
        a.z += __shfl_xor(a.z, 16); a.w += __shfl_xor(a.w, 16);
        a.x += __shfl_xor(a.x, 32); a.y += __shfl_xor(a.y, 32);
        a.z += __shfl_xor(a.z, 32); a.w += __shfl_xor(a.w, 32);
        if (eg == 0) {
            float invd = 1.f / fmaxf((float)len, 1.f);
            M[(size_t)node * D4 + l16] =
                make_float4(a.x * invd, a.y * invd, a.z * invd, a.w * invd);
        }
    }
}

// ---------------- SAGE dense: out = relu?(M@Wl.T + h@Wr.T + bl) ----------------

__global__ __launch_bounds__(256) void sage_dense2(const f4* __restrict__ M4,
                                                   const f4* __restrict__ h4,
                                                   const float* __restrict__ Wl,
                                                   const float* __restrict__ bl,
                                                   const float* __restrict__ Wr,
                                                   f4* __restrict__ out4,
                                                   int relu_flag, int n) {
    __shared__ float At[64 * PITCH];
    __shared__ float Wt[64 * PITCH];
    int t = threadIdx.x;
    int nb = blockIdx.x * 64;
    int r = t >> 4, c = t & 15;
    float acc[4][4] = {{0.f}};
    stageT(At, M4 + (size_t)nb * 16, t, n - nb);
    stageT(Wt, (const f4*)Wl, t, 64);
    __syncthreads();
    TILE_MM(At, Wt, acc, r, c, 64)
    __syncthreads();
    stageT(At, h4 + (size_t)nb * 16, t, n - nb);
    stageT(Wt, (const f4*)Wr, t, 64);
    __syncthreads();
    TILE_MM(At, Wt, acc, r, c, 64)
    f4 bv = ((const f4*)bl)[c];
#pragma unroll
    for (int i = 0; i < 4; i++) {
        int node = nb + r * 4 + i;
        if (node < n) {
            f4 o = make_float4(acc[i][0] + bv.x, acc[i][1] + bv.y,
                               acc[i][2] + bv.z, acc[i][3] + bv.w);
            if (relu_flag) {
                o.x = fmaxf(o.x, 0.f); o.y = fmaxf(o.y, 0.f);
                o.z = fmaxf(o.z, 0.f); o.w = fmaxf(o.w, 0.f);
            }
            out4[(size_t)node * 16 + c] = o;
        }
    }
}

// ---------------- GAT dense: ht = h@W.T ; as = ht.a_src ; ad = ht.a_dst ----------------

__global__ __launch_bounds__(256) void gat_transform(const f4* __restrict__ h4,
                                                     const float* __restrict__ W,
                                                     const float* __restrict__ a_src,
                                                     const float* __restrict__ a_dst,
                                                     f4* __restrict__ ht4,
                                                     float* __restrict__ as_,
                                                     float* __restrict__ ad_, int n) {
    __shared__ float At[64 * PITCH];
    __shared__ float Wt[64 * PITCH];
    __shared__ float ps[16][68];
    __shared__ float pd[16][68];
    int t = threadIdx.x;
    int nb = blockIdx.x * 64;
    int r = t >> 4, c = t & 15;
    stageT(At, h4 + (size_t)nb * 16, t, n - nb);
    stageT(Wt, (const f4*)W, t, 64);
    __syncthreads();
    float acc[4][4] = {{0.f}};
    TILE_MM(At, Wt, acc, r, c, 64)
    f4 sv = ((const f4*)a_src)[c];
    f4 dv = ((const f4*)a_dst)[c];
#pragma unroll
    for (int i = 0; i < 4; i++) {
        int node = nb + r * 4 + i;
        if (node < n)
            ht4[(size_t)node * 16 + c] =
                make_float4(acc[i][0], acc[i][1], acc[i][2], acc[i][3]);
        ps[c][r * 4 + i] = acc[i][0] * sv.x + acc[i][1] * sv.y +
                           acc[i][2] * sv.z + acc[i][3] * sv.w;
        pd[c][r * 4 + i] = acc[i][0] * dv.x + acc[i][1] * dv.y +
                           acc[i][2] * dv.z + acc[i][3] * dv.w;
    }
    __syncthreads();
    if (t < 64) {
        int node = nb + t;
        if (node < n) {
            float s = 0.f, d = 0.f;
#pragma unroll
            for (int cc = 0; cc < 16; cc++) {
                s += ps[cc][t];
                d += pd[cc][t];
            }
            as_[node] = s;
            ad_[node] = d;
        }
    }
}

// ---------------- GAT gather: one wave per node, exact online softmax, 16 edges/iter ----------------

__global__ __launch_bounds__(256) void gat_gather(const int* __restrict__ rowptr,
                                                  const int* __restrict__ col,
                                                  const float* __restrict__ as_,
                                                  const float* __restrict__ ad_,
                                                  const f4* __restrict__ ht,
                                                  const float* __restrict__ b,
                                                  f4* __restrict__ out,
                                                  int relu_flag, int n) {
    int lane = threadIdx.x & 63;
    int eg = lane >> 4, l16 = lane & 15;
    int wave = (blockIdx.x * 256 + threadIdx.x) >> 6;
    int nw = (gridDim.x * 256) >> 6;
    const f4* b4 = (const f4*)b;
    for (int node = wave; node < n; node += nw) {
        int start = rowptr[node], end = rowptr[node + 1];
        int len = end - start;
        float ad_n = ad_[node];
        float e_self = leaky02(as_[node] + ad_n);
        float m = e_self;                       // wave-uniform running max
        float zp = (eg == 0) ? 1.f : 0.f;       // per-group z partial
        f4 acc = {0, 0, 0, 0};
        if (eg == 0) acc = ht[(size_t)node * D4 + l16];
        int main16 = len & ~15;
        int o = 0;
        for (; o < main16; o += 16) {
            int i0 = start + o + eg;
            int s0 = __builtin_nontemporal_load(&col[i0]);
            int s1 = __builtin_nontemporal_load(&col[i0 + 4]);
            int s2 = __builtin_nontemporal_load(&col[i0 + 8]);
            int s3 = __builtin_nontemporal_load(&col[i0 + 12]);
            f4 r0 = ht[(size_t)s0 * D4 + l16];
            f4 r1 = ht[(size_t)s1 * D4 + l16];
            f4 r2 = ht[(size_t)s2 * D4 + l16];
            f4 r3 = ht[(size_t)s3 * D4 + l16];
            float e0 = leaky02(as_[s0] + ad_n);
            float e1 = leaky02(as_[s1] + ad_n);
            float e2 = leaky02(as_[s2] + ad_n);
            float e3 = leaky02(as_[s3] + ad_n);
            float em = fmaxf(fmaxf(e0, e1), fmaxf(e2, e3));
            em = fmaxf(em, __shfl_xor(em, 16));
            em = fmaxf(em, __shfl_xor(em, 32));
            if (em > m) {
                float sc = __expf(m - em);
                zp *= sc;
                acc = f4scale(acc, sc);
                m = em;
            }
            float p0 = __expf(e0 - m);
            float p1 = __expf(e1 - m);
            float p2 = __expf(e2 - m);
            float p3 = __expf(e3 - m);
            zp += (p0 + p1) + (p2 + p3);
            acc = f4fma(p0, r0, acc);
            acc = f4fma(p1, r1, acc);
            acc = f4fma(p2, r2, acc);
            acc = f4fma(p3, r3, acc);
        }
        int rem = len - o;
        if (rem > 0) {
            int i0 = start + o;
            bool v0 = eg < rem, v1 = eg + 4 < rem, v2 = eg + 8 < rem, v3 = eg + 12 < rem;
            int s0 = v0 ? col[i0 + eg] : 0;
            int s1 = v1 ? col[i0 + 4 + eg] : 0;
            int s2 = v2 ? col[i0 + 8 + eg] : 0;
            int s3 = v3 ? col[i0 + 12 + eg] : 0;
            float e0 = v0 ? leaky02(as_[s0] + ad_n) : -3.4e38f;
            float e1 = v1 ? leaky02(as_[s1] + ad_n) : -3.4e38f;
            float e2 = v2 ? leaky02(as_[s2] + ad_n) : -3.4e38f;
            float e3 = v3 ? leaky02(as_[s3] + ad_n) : -3.4e38f;
            float em = fmaxf(fmaxf(e0, e1), fmaxf(e2, e3));
            em = fmaxf(em, __shfl_xor(em, 16));
            em = fmaxf(em, __shfl_xor(em, 32));
            if (em > m) {
                float sc = __expf(m - em);
                zp *= sc;
                acc = f4scale(acc, sc);
                m = em;
            }
            float p0 = v0 ? __expf(e0 - m) : 0.f;
            float p1 = v1 ? __expf(e1 - m) : 0.f;
            float p2 = v2 ? __expf(e2 - m) : 0.f;
            float p3 = v3 ? __expf(e3 - m) : 0.f;
            zp += (p0 + p1) + (p2 + p3);
            if (v0) acc = f4fma(p0, ht[(size_t)s0 * D4 + l16], acc);
            if (v1) acc = f4fma(p1, ht[(size_t)s1 * D4 + l16], acc);
            if (v2) acc = f4fma(p2, ht[(size_t)s2 * D4 + l16], acc);
            if (v3) acc = f4fma(p3, ht[(size_t)s3 * D4 + l16], acc);
        }
        float z = zp;
        z += __shfl_xor(z, 16);
        z += __shfl_xor(z, 32);
        acc.x += __shfl_xor(acc.x, 16); acc.y += __shfl_xor(acc.y, 16);
        acc.z += __shfl_xor(acc.z, 16); acc.w += __shfl_xor(acc.w, 16);
        acc.x += __shfl_xor(acc.x, 32); acc.y += __shfl_xor(acc.y, 32);
        acc.z += __shfl_xor(acc.z, 32); acc.w += __shfl_xor(acc.w, 32);
        if (eg == 0) {
            float rz = 1.f / z;
            f4 bb = b4[l16];
            f4 o4 = make_float4(fmaf(acc.x, rz, bb.x), fmaf(acc.y, rz, bb.y),
                                fmaf(acc.z, rz, bb.z), fmaf(acc.w, rz, bb.w));
            if (relu_flag) {
                o4.x = fmaxf(o4.x, 0.f); o4.y = fmaxf(o4.y, 0.f);
                o4.z = fmaxf(o4.z, 0.f); o4.w = fmaxf(o4.w, 0.f);
            }
            out[(size_t)node * D4 + l16] = o4;
        }
    }
}

// ---------------- MLP: tiled 3-layer chain in one kernel ----------------

__global__ __launch_bounds__(256) void mlp_kernel(const f4* __restrict__ h4,
                                                  const float* __restrict__ W1,
                                                  const float* __restrict__ b1,
                                                  const float* __restrict__ W2,
                                                  const float* __restrict__ b2,
                                                  const float* __restrict__ W3,
                                                  const float* __restrict__ b3,
                                                  float* __restrict__ out, int n) {
    __shared__ float At[64 * PITCH];   // h tile, then v1T
    __shared__ float Wt[64 * PITCH];   // W1t, then W2t, then W3t
    __shared__ float V2[32 * PITCH];   // v2T
    int t = threadIdx.x;
    int nb = blockIdx.x * 64;
    int r = t >> 4, c = t & 15;
    stageT(At, h4 + (size_t)nb * 16, t, n - nb);
    stageT(Wt, (const f4*)W1, t, 64);
    __syncthreads();
    float a1v[4][4] = {{0.f}};
    TILE_MM(At, Wt, a1v, r, c, 64)
    f4 b1v = ((const f4*)b1)[c];
    __syncthreads();
    {
        float bb[4] = {b1v.x, b1v.y, b1v.z, b1v.w};
#pragma unroll
        for (int i = 0; i < 4; i++)
#pragma unroll
            for (int j = 0; j < 4; j++)
                At[(c * 4 + j) * PITCH + r * 4 + i] = fmaxf(a1v[i][j] + bb[j], 0.f);
    }
    stageT(Wt, (const f4*)W2, t, 32);   // W2 is [32][64]
    __syncthreads();
    // layer 2: 64 -> 32, relu; thread owns 4 nodes x 2 outs (o = 2c, 2c+1)
    float a2v[4][2] = {{0.f}};
    for (int k = 0; k < 64; k++) {
        f4 a = *(const f4*)&At[k * PITCH + r * 4];
        float w0 = Wt[k * PITCH + c * 2];
        float w1 = Wt[k * PITCH + c * 2 + 1];
        a2v[0][0] = fmaf(a.x, w0, a2v[0][0]); a2v[0][1] = fmaf(a.x, w1, a2v[0][1]);
        a2v[1][0] = fmaf(a.y, w0, a2v[1][0]); a2v[1][1] = fmaf(a.y, w1, a2v[1][1]);
        a2v[2][0] = fmaf(a.z, w0, a2v[2][0]); a2v[2][1] = fmaf(a.z, w1, a2v[2][1]);
        a2v[3][0] = fmaf(a.w, w0, a2v[3][0]); a2v[3][1] = fmaf(a.w, w1, a2v[3][1]);
    }
    float b20 = b2[c * 2], b21 = b2[c * 2 + 1];
    __syncthreads();
#pragma unroll
    for (int i = 0; i < 4; i++) {
        V2[(c * 2 + 0) * PITCH + r * 4 + i] = fmaxf(a2v[i][0] + b20, 0.f);
        V2[(c * 2 + 1) * PITCH + r * 4 + i] = fmaxf(a2v[i][1] + b21, 0.f);
    }
    if (t < 128) {
        int row = t >> 3, kq = t & 7;
        f4 w = ((const f4*)W3)[row * 8 + kq];
        int k0 = kq * 4;
        Wt[(k0 + 0) * PITCH + row] = w.x;
        Wt[(k0 + 1) * PITCH + row] = w.y;
        Wt[(k0 + 2) * PITCH + row] = w.z;
        Wt[(k0 + 3) * PITCH + row] = w.w;
    }
    __syncthreads();
    // layer 3: 32 -> 16; thread owns 4 nodes x 1 out (o = c)
    float a3v[4] = {0.f, 0.f, 0.f, 0.f};
    for (int k = 0; k < 32; k++) {
        f4 a = *(const f4*)&V2[k * PITCH + r * 4];
        float w = Wt[k * PITCH + c];
        a3v[0] = fmaf(a.x, w, a3v[0]);
        a3v[1] = fmaf(a.y, w, a3v[1]);
        a3v[2] = fmaf(a.z, w, a3v[2]);
        a3v[3] = fmaf(a.w, w, a3v[3]);
    }
    float b3v = b3[c];
#pragma unroll
    for (int i = 0; i < 4; i++) {
        int node = nb + r * 4 + i;
        if (node < n) out[(size_t)node * 16 + c] = a3v[i] + b3v;
    }
}

// ---------------- launch ----------------

extern "C" void kernel_launch(void* const* d_in, const int* in_sizes, int n_in,
                              void* d_out, int out_size, void* d_ws, size_t ws_size,
                              hipStream_t stream) {
    const int n  = in_sizes[0] / D;      // 100000
    const int ne = in_sizes[1] / 2;      // 1600000

    const float* x        = (const float*)d_in[0];
    const int*   ei       = (const int*)d_in[1];
    const int*   src      = ei;
    const int*   dst      = ei + ne;
    const float* sage_Wl  = (const float*)d_in[2];
    const float* sage_bl  = (const float*)d_in[3];
    const float* sage_Wr  = (const float*)d_in[4];
    const float* gat_W    = (const float*)d_in[5];
    const float* gat_asrc = (const float*)d_in[6];
    const float* gat_adst = (const float*)d_in[7];
    const float* gat_b    = (const float*)d_in[8];
    const float* W1 = (const float*)d_in[9];
    const float* b1 = (const float*)d_in[10];
    const float* W2 = (const float*)d_in[11];
    const float* b2 = (const float*)d_in[12];
    const float* W3 = (const float*)d_in[13];
    const float* b3 = (const float*)d_in[14];
    float* out = (float*)d_out;

    // workspace layout (4B units, all offsets 16B-aligned)
    int*   cnt      = (int*)d_ws;                    // n
    int*   incl     = cnt + n;                       // n
    int*   rowptr   = incl + n;                      // n+4
    int*   cursor   = rowptr + n + 4;                // n
    int*   partials = cursor + n;                    // 1024
    int*   col      = partials + 1024;               // ne
    float* as_      = (float*)(col + ne);            // n
    float* ad_      = as_ + n;                       // n
    float* M        = ad_ + n;                       // n*D (sage mean / GAT ht)
    float* bufA     = M + (size_t)n * D;             // n*D
    float* bufB     = bufA + (size_t)n * D;          // n*D

    const int gridE  = (ne + 255) / 256;
    const int nb     = (n + SCAN_BS - 1) / SCAN_BS;
    const int gridG  = 6144;                         // one wave per node, grid-stride
    const int gridM  = (n + 63) / 64;                // 64-node tiles

    // ---- CSR build ----
    hipMemsetAsync(cnt, 0, (size_t)n * 4, stream);
    hist_kernel<<<gridE, 256, 0, stream>>>(dst, cnt, ne);
    scan1_kernel<<<nb, SCAN_BS, 0, stream>>>(cnt, incl, partials, n);
    scan2_kernel<<<1, 1024, 0, stream>>>(partials, nb);
    scan3_kernel<<<nb, SCAN_BS, 0, stream>>>(cnt, incl, partials, rowptr, cursor, n, ne);
    fill_kernel<<<gridE, 256, 0, stream>>>(src, dst, cursor, col, ne);

    // ---- 4 SAGE layers (gather-first, reference order) ----
    const float* cur = x;
    float* nxt = bufA;
    for (int l = 0; l < 4; l++) {
        sage_gather<<<gridG, 256, 0, stream>>>((const f4*)cur, rowptr, col, (f4*)M, n);
        sage_dense2<<<gridM, 256, 0, stream>>>((const f4*)M, (const f4*)cur,
                                               sage_Wl + (size_t)l * D * D,
                                               sage_bl + (size_t)l * D,
                                               sage_Wr + (size_t)l * D * D,
                                               (f4*)nxt, (l < 3) ? 1 : 0, n);
        cur = nxt;
        nxt = (nxt == bufA) ? bufB : bufA;
    }
    // cur == bufB

    // ---- 4 GAT layers (in-place on bufB, ht reuses M) ----
    float* gin = bufB;
    for (int l = 0; l < 4; l++) {
        gat_transform<<<gridM, 256, 0, stream>>>((const f4*)gin,
                                                 gat_W + (size_t)l * D * D,
                                                 gat_asrc + (size_t)l * D,
                                                 gat_adst + (size_t)l * D,
                                                 (f4*)M, as_, ad_, n);
        gat_gather<<<gridG, 256, 0, stream>>>(rowptr, col, as_, ad_,
                                              (const f4*)M,
                                              gat_b + (size_t)l * D, (f4*)gin,
                                              (l < 3) ? 1 : 0, n);
    }

    // ---- projection MLP ----
    mlp_kernel<<<gridM, 256, 0, stream>>>((const f4*)gin, W1, b1, W2, b2, W3, b3, out, n);
}

// Round 13
// 904.846 us; speedup vs baseline: 1.2187x; 1.2187x over previous
//
#include <hip/hip_runtime.h>
#include <hip/hip_fp16.h>

#define D 64
#define D4 16   // D/4 float4 per row
#define PITCH 68  // LDS tile pitch: 16B-aligned b128 rows, <=2-way banks

typedef float4 f4;
typedef unsigned int u32;

__device__ __forceinline__ float leaky02(float x) { return (x >= 0.f) ? x : 0.2f * x; }

__device__ __forceinline__ f4 f4add(f4 a, f4 b) {
    return make_float4(a.x + b.x, a.y + b.y, a.z + b.z, a.w + b.w);
}
__device__ __forceinline__ f4 f4fma(float s, f4 v, f4 a) {
    return make_float4(fmaf(s, v.x, a.x), fmaf(s, v.y, a.y), fmaf(s, v.z, a.z), fmaf(s, v.w, a.w));
}
__device__ __forceinline__ f4 f4scale(f4 a, float s) {
    return make_float4(a.x * s, a.y * s, a.z * s, a.w * s);
}

__device__ __forceinline__ u32 pack2(float a, float b) {
    __half2 h = __floats2half2_rn(a, b);
    return *reinterpret_cast<u32*>(&h);
}
__device__ __forceinline__ uint2 pack4(float a, float b, float c, float d) {
    uint2 u;
    u.x = pack2(a, b);
    u.y = pack2(c, d);
    return u;
}
__device__ __forceinline__ f4 h2f4(uint2 u) {
    __half2 ha = *reinterpret_cast<__half2*>(&u.x);
    __half2 hb = *reinterpret_cast<__half2*>(&u.y);
    float2 fa = __half22float2(ha);
    float2 fb = __half22float2(hb);
    return make_float4(fa.x, fa.y, fb.x, fb.y);
}

// ---------------- CSR build ----------------

__global__ __launch_bounds__(256) void hist_kernel(const int* __restrict__ dst,
                                                   int* __restrict__ cnt, int ne) {
    int e = blockIdx.x * blockDim.x + threadIdx.x;
    if (e < ne) atomicAdd(&cnt[dst[e]], 1);
}

#define SCAN_BS 256
__global__ __launch_bounds__(SCAN_BS) void scan1_kernel(const int* __restrict__ cnt,
                                                        int* __restrict__ incl,
                                                        int* __restrict__ partials, int n) {
    __shared__ int sm[SCAN_BS];
    int g = blockIdx.x * SCAN_BS + threadIdx.x;
    int v = (g < n) ? cnt[g] : 0;
    sm[threadIdx.x] = v;
    __syncthreads();
    for (int off = 1; off < SCAN_BS; off <<= 1) {
        int t = (threadIdx.x >= off) ? sm[threadIdx.x - off] : 0;
        __syncthreads();
        sm[threadIdx.x] += t;
        __syncthreads();
    }
    if (g < n) incl[g] = sm[threadIdx.x];
    if (threadIdx.x == SCAN_BS - 1) partials[blockIdx.x] = sm[threadIdx.x];
}

__global__ __launch_bounds__(1024) void scan2_kernel(int* __restrict__ partials, int nb) {
    __shared__ int sm[1024];
    int t = threadIdx.x;
    int v = (t < nb) ? partials[t] : 0;
    sm[t] = v;
    __syncthreads();
    for (int off = 1; off < 1024; off <<= 1) {
        int x = (t >= off) ? sm[t - off] : 0;
        __syncthreads();
        sm[t] += x;
        __syncthreads();
    }
    if (t < nb) partials[t] = sm[t] - v;   // exclusive
}

__global__ __launch_bounds__(SCAN_BS) void scan3_kernel(const int* __restrict__ cnt,
                                                        const int* __restrict__ incl,
                                                        const int* __restrict__ partials,
                                                        int* __restrict__ rowptr,
                                                        int* __restrict__ cursor, int n, int ne) {
    int g = blockIdx.x * SCAN_BS + threadIdx.x;
    if (g < n) {
        int rp = incl[g] - cnt[g] + partials[blockIdx.x];
        rowptr[g] = rp;
        cursor[g] = rp;
    }
    if (g == 0) rowptr[n] = ne;
}

__global__ __launch_bounds__(256) void fill_kernel(const int* __restrict__ src,
                                                   const int* __restrict__ dst,
                                                   int* __restrict__ cursor,
                                                   int* __restrict__ col, int ne) {
    int e = blockIdx.x * blockDim.x + threadIdx.x;
    if (e < ne) {
        int pos = atomicAdd(&cursor[dst[e]], 1);
        col[pos] = src[e];
    }
}

// ---------------- fp32 -> fp16 row conversion ----------------

__global__ __launch_bounds__(256) void to_half(const float* __restrict__ in,
                                               uint2* __restrict__ out, int total4) {
    int i = blockIdx.x * 256 + threadIdx.x;
    if (i < total4) {
        f4 v = *(const f4*)&in[i * 4];
        out[i] = pack4(v.x, v.y, v.z, v.w);
    }
}

// ---------------- LDS staging: T[k][row] transposed from row-major G[rows][64] ----------------

__device__ __forceinline__ void stageT(float* __restrict__ T, const f4* __restrict__ G4,
                                       int t, int valid_rows) {
    int row = t >> 2;
    int kq0 = t & 3;
#pragma unroll
    for (int c = 0; c < 4; c++) {
        int kq = kq0 + 4 * c;
        f4 r = make_float4(0.f, 0.f, 0.f, 0.f);
        if (row < valid_rows) r = G4[(size_t)row * 16 + kq];
        int k0 = kq * 4;
        T[(k0 + 0) * PITCH + row] = r.x;
        T[(k0 + 1) * PITCH + row] = r.y;
        T[(k0 + 2) * PITCH + row] = r.z;
        T[(k0 + 3) * PITCH + row] = r.w;
    }
}

// 4x4 register-tile inner product over K: acc[i][j] += At[k][4r+i]*Wt[k][4c+j]
#define TILE_MM(At, Wt, acc, r, c, KDIM)                                      \
    for (int k = 0; k < KDIM; k++) {                                          \
        f4 a = *(const f4*)&(At)[k * PITCH + (r) * 4];                        \
        f4 w = *(const f4*)&(Wt)[k * PITCH + (c) * 4];                        \
        acc[0][0] = fmaf(a.x, w.x, acc[0][0]);                                \
        acc[0][1] = fmaf(a.x, w.y, acc[0][1]);                                \
        acc[0][2] = fmaf(a.x, w.z, acc[0][2]);                                \
        acc[0][3] = fmaf(a.x, w.w, acc[0][3]);                                \
        acc[1][0] = fmaf(a.y, w.x, acc[1][0]);                                \
        acc[1][1] = fmaf(a.y, w.y, acc[1][1]);                                \
        acc[1][2] = fmaf(a.y, w.z, acc[1][2]);                                \
        acc[1][3] = fmaf(a.y, w.w, acc[1][3]);                                \
        acc[2][0] = fmaf(a.z, w.x, acc[2][0]);                                \
        acc[2][1] = fmaf(a.z, w.y, acc[2][1]);                                \
        acc[2][2] = fmaf(a.z, w.z, acc[2][2]);                                \
        acc[2][3] = fmaf(a.z, w.w, acc[2][3]);                                \
        acc[3][0] = fmaf(a.w, w.x, acc[3][0]);                                \
        acc[3][1] = fmaf(a.w, w.y, acc[3][1]);                                \
        acc[3][2] = fmaf(a.w, w.z, acc[3][2]);                                \
        acc[3][3] = fmaf(a.w, w.w, acc[3][3]);                                \
    }

// ---------------- SAGE gather: M[i] = mean_{j in N(i)} h[j]  (fp16 rows) ----------------
// One wave per node; 4 edge-groups x 16 feature-lanes; 16 edges in flight.

__global__ __launch_bounds__(256) void sage_gather(const uint2* __restrict__ Hh,
                                                   const int* __restrict__ rowptr,
                                                   const int* __restrict__ col,
                                                   f4* __restrict__ M, int n) {
    int lane = threadIdx.x & 63;
    int eg = lane >> 4, l16 = lane & 15;
    int wave = (blockIdx.x * 256 + threadIdx.x) >> 6;
    int nw = (gridDim.x * 256) >> 6;
    for (int node = wave; node < n; node += nw) {
        int start = rowptr[node], end = rowptr[node + 1];
        int len = end - start;
        f4 a0 = {0, 0, 0, 0}, a1 = {0, 0, 0, 0}, a2 = {0, 0, 0, 0}, a3 = {0, 0, 0, 0};
        int main16 = len & ~15;
        int o = 0;
        for (; o < main16; o += 16) {
            int i0 = start + o + eg;
            int s0 = col[i0];
            int s1 = col[i0 + 4];
            int s2 = col[i0 + 8];
            int s3 = col[i0 + 12];
            uint2 v0 = Hh[(size_t)s0 * D4 + l16];
            uint2 v1 = Hh[(size_t)s1 * D4 + l16];
            uint2 v2 = Hh[(size_t)s2 * D4 + l16];
            uint2 v3 = Hh[(size_t)s3 * D4 + l16];
            a0 = f4add(a0, h2f4(v0)); a1 = f4add(a1, h2f4(v1));
            a2 = f4add(a2, h2f4(v2)); a3 = f4add(a3, h2f4(v3));
        }
        int rem = len - o;
        if (rem > 0) {
            int i0 = start + o;
            if (eg < rem)      a0 = f4add(a0, h2f4(Hh[(size_t)col[i0 + eg] * D4 + l16]));
            if (eg + 4 < rem)  a1 = f4add(a1, h2f4(Hh[(size_t)col[i0 + 4 + eg] * D4 + l16]));
            if (eg + 8 < rem)  a2 = f4add(a2, h2f4(Hh[(size_t)col[i0 + 8 + eg] * D4 + l16]));
            if (eg + 12 < rem) a3 = f4add(a3, h2f4(Hh[(size_t)col[i0 + 12 + eg] * D4 + l16]));
        }
        f4 a = f4add(f4add(a0, a1), f4add(a2, a3));
        a.x += __shfl_xor(a.x, 16); a.y += __shfl_xor(a.y, 16);
        a.z += __shfl_xor(a.z, 16); a.w += __shfl_xor(a.w, 16);
        a.x += __shfl_xor(a.x, 32); a.y += __shfl_xor(a.y, 32);
        a.z += __shfl_xor(a.z, 32); a.w += __shfl_xor(a.w, 32);
        if (eg == 0) {
            float invd = 1.f / fmaxf((float)len, 1.f);
            M[(size_t)node * D4 + l16] =
                make_float4(a.x * invd, a.y * invd, a.z * invd, a.w * invd);
        }
    }
}

// ---------------- SAGE dense: out = relu?(M@Wl.T + h@Wr.T + bl), + fp16 copy ----------------

__global__ __launch_bounds__(256) void sage_dense2(const f4* __restrict__ M4,
                                                   const f4* __restrict__ h4,
                                                   const float* __restrict__ Wl,
                                                   const float* __restrict__ bl,
                                                   const float* __restrict__ Wr,
                                                   f4* __restrict__ out4,
                                                   uint2* __restrict__ outh,
                                                   int relu_flag, int n) {
    __shared__ float At[64 * PITCH];
    __shared__ float Wt[64 * PITCH];
    int t = threadIdx.x;
    int nb = blockIdx.x * 64;
    int r = t >> 4, c = t & 15;
    float acc[4][4] = {{0.f}};
    stageT(At, M4 + (size_t)nb * 16, t, n - nb);
    stageT(Wt, (const f4*)Wl, t, 64);
    __syncthreads();
    TILE_MM(At, Wt, acc, r, c, 64)
    __syncthreads();
    stageT(At, h4 + (size_t)nb * 16, t, n - nb);
    stageT(Wt, (const f4*)Wr, t, 64);
    __syncthreads();
    TILE_MM(At, Wt, acc, r, c, 64)
    f4 bv = ((const f4*)bl)[c];
#pragma unroll
    for (int i = 0; i < 4; i++) {
        int node = nb + r * 4 + i;
        if (node < n) {
            f4 o = make_float4(acc[i][0] + bv.x, acc[i][1] + bv.y,
                               acc[i][2] + bv.z, acc[i][3] + bv.w);
            if (relu_flag) {
                o.x = fmaxf(o.x, 0.f); o.y = fmaxf(o.y, 0.f);
                o.z = fmaxf(o.z, 0.f); o.w = fmaxf(o.w, 0.f);
            }
            out4[(size_t)node * 16 + c] = o;
            outh[(size_t)node * 16 + c] = pack4(o.x, o.y, o.z, o.w);
        }
    }
}

// ---------------- GAT dense: ht(fp16) = h@W.T ; as = ht.a_src ; ad = ht.a_dst ----------------

__global__ __launch_bounds__(256) void gat_transform(const f4* __restrict__ h4,
                                                     const float* __restrict__ W,
                                                     const float* __restrict__ a_src,
                                                     const float* __restrict__ a_dst,
                                                     uint2* __restrict__ hth,
                                                     float* __restrict__ as_,
                                                     float* __restrict__ ad_, int n) {
    __shared__ float At[64 * PITCH];
    __shared__ float Wt[64 * PITCH];
    __shared__ float ps[16][68];
    __shared__ float pd[16][68];
    int t = threadIdx.x;
    int nb = blockIdx.x * 64;
    int r = t >> 4, c = t & 15;
    stageT(At, h4 + (size_t)nb * 16, t, n - nb);
    stageT(Wt, (const f4*)W, t, 64);
    __syncthreads();
    float acc[4][4] = {{0.f}};
    TILE_MM(At, Wt, acc, r, c, 64)
    f4 sv = ((const f4*)a_src)[c];
    f4 dv = ((const f4*)a_dst)[c];
#pragma unroll
    for (int i = 0; i < 4; i++) {
        int node = nb + r * 4 + i;
        if (node < n)
            hth[(size_t)node * 16 + c] = pack4(acc[i][0], acc[i][1], acc[i][2], acc[i][3]);
        ps[c][r * 4 + i] = acc[i][0] * sv.x + acc[i][1] * sv.y +
                           acc[i][2] * sv.z + acc[i][3] * sv.w;
        pd[c][r * 4 + i] = acc[i][0] * dv.x + acc[i][1] * dv.y +
                           acc[i][2] * dv.z + acc[i][3] * dv.w;
    }
    __syncthreads();
    if (t < 64) {
        int node = nb + t;
        if (node < n) {
            float s = 0.f, d = 0.f;
#pragma unroll
            for (int cc = 0; cc < 16; cc++) {
                s += ps[cc][t];
                d += pd[cc][t];
            }
            as_[node] = s;
            ad_[node] = d;
        }
    }
}

// ---------------- GAT gather: one wave per node, exact online softmax, fp16 rows ----------------

__global__ __launch_bounds__(256) void gat_gather(const int* __restrict__ rowptr,
                                                  const int* __restrict__ col,
                                                  const float* __restrict__ as_,
                                                  const float* __restrict__ ad_,
                                                  const uint2* __restrict__ Hh,
                                                  const float* __restrict__ b,
                                                  f4* __restrict__ out,
                                                  int relu_flag, int n) {
    int lane = threadIdx.x & 63;
    int eg = lane >> 4, l16 = lane & 15;
    int wave = (blockIdx.x * 256 + threadIdx.x) >> 6;
    int nw = (gridDim.x * 256) >> 6;
    const f4* b4 = (const f4*)b;
    for (int node = wave; node < n; node += nw) {
        int start = rowptr[node], end = rowptr[node + 1];
        int len = end - start;
        float ad_n = ad_[node];
        float e_self = leaky02(as_[node] + ad_n);
        float m = e_self;                       // wave-uniform running max
        float zp = (eg == 0) ? 1.f : 0.f;       // per-group z partial
        f4 acc = {0, 0, 0, 0};
        if (eg == 0) acc = h2f4(Hh[(size_t)node * D4 + l16]);
        int main16 = len & ~15;
        int o = 0;
        for (; o < main16; o += 16) {
            int i0 = start + o + eg;
            int s0 = col[i0];
            int s1 = col[i0 + 4];
            int s2 = col[i0 + 8];
            int s3 = col[i0 + 12];
            uint2 v0 = Hh[(size_t)s0 * D4 + l16];
            uint2 v1 = Hh[(size_t)s1 * D4 + l16];
            uint2 v2 = Hh[(size_t)s2 * D4 + l16];
            uint2 v3 = Hh[(size_t)s3 * D4 + l16];
            float e0 = leaky02(as_[s0] + ad_n);
            float e1 = leaky02(as_[s1] + ad_n);
            float e2 = leaky02(as_[s2] + ad_n);
            float e3 = leaky02(as_[s3] + ad_n);
            float em = fmaxf(fmaxf(e0, e1), fmaxf(e2, e3));
            em = fmaxf(em, __shfl_xor(em, 16));
            em = fmaxf(em, __shfl_xor(em, 32));
            if (em > m) {
                float sc = __expf(m - em);
                zp *= sc;
                acc = f4scale(acc, sc);
                m = em;
            }
            float p0 = __expf(e0 - m);
            float p1 = __expf(e1 - m);
            float p2 = __expf(e2 - m);
            float p3 = __expf(e3 - m);
            zp += (p0 + p1) + (p2 + p3);
            acc = f4fma(p0, h2f4(v0), acc);
            acc = f4fma(p1, h2f4(v1), acc);
            acc = f4fma(p2, h2f4(v2), acc);
            acc = f4fma(p3, h2f4(v3), acc);
        }
        int rem = len - o;
        if (rem > 0) {
            int i0 = start + o;
            bool v0b = eg < rem, v1b = eg + 4 < rem, v2b = eg + 8 < rem, v3b = eg + 12 < rem;
            int s0 = v0b ? col[i0 + eg] : 0;
            int s1 = v1b ? col[i0 + 4 + eg] : 0;
            int s2 = v2b ? col[i0 + 8 + eg] : 0;
            int s3 = v3b ? col[i0 + 12 + eg] : 0;
            float e0 = v0b ? leaky02(as_[s0] + ad_n) : -3.4e38f;
            float e1 = v1b ? leaky02(as_[s1] + ad_n) : -3.4e38f;
            float e2 = v2b ? leaky02(as_[s2] + ad_n) : -3.4e38f;
            float e3 = v3b ? leaky02(as_[s3] + ad_n) : -3.4e38f;
            float em = fmaxf(fmaxf(e0, e1), fmaxf(e2, e3));
            em = fmaxf(em, __shfl_xor(em, 16));
            em = fmaxf(em, __shfl_xor(em, 32));
            if (em > m) {
                float sc = __expf(m - em);
                zp *= sc;
                acc = f4scale(acc, sc);
                m = em;
            }
            float p0 = v0b ? __expf(e0 - m) : 0.f;
            float p1 = v1b ? __expf(e1 - m) : 0.f;
            float p2 = v2b ? __expf(e2 - m) : 0.f;
            float p3 = v3b ? __expf(e3 - m) : 0.f;
            zp += (p0 + p1) + (p2 + p3);
            if (v0b) acc = f4fma(p0, h2f4(Hh[(size_t)s0 * D4 + l16]), acc);
            if (v1b) acc = f4fma(p1, h2f4(Hh[(size_t)s1 * D4 + l16]), acc);
            if (v2b) acc = f4fma(p2, h2f4(Hh[(size_t)s2 * D4 + l16]), acc);
            if (v3b) acc = f4fma(p3, h2f4(Hh[(size_t)s3 * D4 + l16]), acc);
        }
        float z = zp;
        z += __shfl_xor(z, 16);
        z += __shfl_xor(z, 32);
        acc.x += __shfl_xor(acc.x, 16); acc.y += __shfl_xor(acc.y, 16);
        acc.z += __shfl_xor(acc.z, 16); acc.w += __shfl_xor(acc.w, 16);
        acc.x += __shfl_xor(acc.x, 32); acc.y += __shfl_xor(acc.y, 32);
        acc.z += __shfl_xor(acc.z, 32); acc.w += __shfl_xor(acc.w, 32);
        if (eg == 0) {
            float rz = 1.f / z;
            f4 bb = b4[l16];
            f4 o4 = make_float4(fmaf(acc.x, rz, bb.x), fmaf(acc.y, rz, bb.y),
                                fmaf(acc.z, rz, bb.z), fmaf(acc.w, rz, bb.w));
            if (relu_flag) {
                o4.x = fmaxf(o4.x, 0.f); o4.y = fmaxf(o4.y, 0.f);
                o4.z = fmaxf(o4.z, 0.f); o4.w = fmaxf(o4.w, 0.f);
            }
            out[(size_t)node * D4 + l16] = o4;
        }
    }
}

// ---------------- MLP: tiled 3-layer chain in one kernel ----------------

__global__ __launch_bounds__(256) void mlp_kernel(const f4* __restrict__ h4,
                                                  const float* __restrict__ W1,
                                                  const float* __restrict__ b1,
                                                  const float* __restrict__ W2,
                                                  const float* __restrict__ b2,
                                                  const float* __restrict__ W3,
                                                  const float* __restrict__ b3,
                                                  float* __restrict__ out, int n) {
    __shared__ float At[64 * PITCH];   // h tile, then v1T
    __shared__ float Wt[64 * PITCH];   // W1t, then W2t, then W3t
    __shared__ float V2[32 * PITCH];   // v2T
    int t = threadIdx.x;
    int nb = blockIdx.x * 64;
    int r = t >> 4, c = t & 15;
    stageT(At, h4 + (size_t)nb * 16, t, n - nb);
    stageT(Wt, (const f4*)W1, t, 64);
    __syncthreads();
    float a1v[4][4] = {{0.f}};
    TILE_MM(At, Wt, a1v, r, c, 64)
    f4 b1v = ((const f4*)b1)[c];
    __syncthreads();
    {
        float bb[4] = {b1v.x, b1v.y, b1v.z, b1v.w};
#pragma unroll
        for (int i = 0; i < 4; i++)
#pragma unroll
            for (int j = 0; j < 4; j++)
                At[(c * 4 + j) * PITCH + r * 4 + i] = fmaxf(a1v[i][j] + bb[j], 0.f);
    }
    stageT(Wt, (const f4*)W2, t, 32);   // W2 is [32][64]
    __syncthreads();
    // layer 2: 64 -> 32, relu; thread owns 4 nodes x 2 outs (o = 2c, 2c+1)
    float a2v[4][2] = {{0.f}};
    for (int k = 0; k < 64; k++) {
        f4 a = *(const f4*)&At[k * PITCH + r * 4];
        float w0 = Wt[k * PITCH + c * 2];
        float w1 = Wt[k * PITCH + c * 2 + 1];
        a2v[0][0] = fmaf(a.x, w0, a2v[0][0]); a2v[0][1] = fmaf(a.x, w1, a2v[0][1]);
        a2v[1][0] = fmaf(a.y, w0, a2v[1][0]); a2v[1][1] = fmaf(a.y, w1, a2v[1][1]);
        a2v[2][0] = fmaf(a.z, w0, a2v[2][0]); a2v[2][1] = fmaf(a.z, w1, a2v[2][1]);
        a2v[3][0] = fmaf(a.w, w0, a2v[3][0]); a2v[3][1] = fmaf(a.w, w1, a2v[3][1]);
    }
    float b20 = b2[c * 2], b21 = b2[c * 2 + 1];
    __syncthreads();
#pragma unroll
    for (int i = 0; i < 4; i++) {
        V2[(c * 2 + 0) * PITCH + r * 4 + i] = fmaxf(a2v[i][0] + b20, 0.f);
        V2[(c * 2 + 1) * PITCH + r * 4 + i] = fmaxf(a2v[i][1] + b21, 0.f);
    }
    if (t < 128) {
        int row = t >> 3, kq = t & 7;
        f4 w = ((const f4*)W3)[row * 8 + kq];
        int k0 = kq * 4;
        Wt[(k0 + 0) * PITCH + row] = w.x;
        Wt[(k0 + 1) * PITCH + row] = w.y;
        Wt[(k0 + 2) * PITCH + row] = w.z;
        Wt[(k0 + 3) * PITCH + row] = w.w;
    }
    __syncthreads();
    // layer 3: 32 -> 16; thread owns 4 nodes x 1 out (o = c)
    float a3v[4] = {0.f, 0.f, 0.f, 0.f};
    for (int k = 0; k < 32; k++) {
        f4 a = *(const f4*)&V2[k * PITCH + r * 4];
        float w = Wt[k * PITCH + c];
        a3v[0] = fmaf(a.x, w, a3v[0]);
        a3v[1] = fmaf(a.y, w, a3v[1]);
        a3v[2] = fmaf(a.z, w, a3v[2]);
        a3v[3] = fmaf(a.w, w, a3v[3]);
    }
    float b3v = b3[c];
#pragma unroll
    for (int i = 0; i < 4; i++) {
        int node = nb + r * 4 + i;
        if (node < n) out[(size_t)node * 16 + c] = a3v[i] + b3v;
    }
}

// ---------------- launch ----------------

extern "C" void kernel_launch(void* const* d_in, const int* in_sizes, int n_in,
                              void* d_out, int out_size, void* d_ws, size_t ws_size,
                              hipStream_t stream) {
    const int n  = in_sizes[0] / D;      // 100000
    const int ne = in_sizes[1] / 2;      // 1600000

    const float* x        = (const float*)d_in[0];
    const int*   ei       = (const int*)d_in[1];
    const int*   src      = ei;
    const int*   dst      = ei + ne;
    const float* sage_Wl  = (const float*)d_in[2];
    const float* sage_bl  = (const float*)d_in[3];
    const float* sage_Wr  = (const float*)d_in[4];
    const float* gat_W    = (const float*)d_in[5];
    const float* gat_asrc = (const float*)d_in[6];
    const float* gat_adst = (const float*)d_in[7];
    const float* gat_b    = (const float*)d_in[8];
    const float* W1 = (const float*)d_in[9];
    const float* b1 = (const float*)d_in[10];
    const float* W2 = (const float*)d_in[11];
    const float* b2 = (const float*)d_in[12];
    const float* W3 = (const float*)d_in[13];
    const float* b3 = (const float*)d_in[14];
    float* out = (float*)d_out;

    // workspace layout (4B units, all offsets 16B-aligned)
    int*   cnt      = (int*)d_ws;                    // n
    int*   incl     = cnt + n;                       // n
    int*   rowptr   = incl + n;                      // n+4
    int*   cursor   = rowptr + n + 4;                // n
    int*   partials = cursor + n;                    // 1024
    int*   col      = partials + 1024;               // ne
    float* as_      = (float*)(col + ne);            // n
    float* ad_      = as_ + n;                       // n
    float* M        = ad_ + n;                       // n*D fp32 (sage mean)
    float* bufA     = M + (size_t)n * D;             // n*D
    float* bufB     = bufA + (size_t)n * D;          // n*D
    uint2* Hh       = (uint2*)(bufB + (size_t)n * D); // n*16 uint2 = n*D halves

    const int gridE  = (ne + 255) / 256;
    const int nb     = (n + SCAN_BS - 1) / SCAN_BS;
    const int gridG  = 4096;                         // one wave per node, grid-stride
    const int gridM  = (n + 63) / 64;                // 64-node tiles
    const int gridC  = (n * D / 4 + 255) / 256;      // to_half

    // ---- CSR build ----
    hipMemsetAsync(cnt, 0, (size_t)n * 4, stream);
    hist_kernel<<<gridE, 256, 0, stream>>>(dst, cnt, ne);
    scan1_kernel<<<nb, SCAN_BS, 0, stream>>>(cnt, incl, partials, n);
    scan2_kernel<<<1, 1024, 0, stream>>>(partials, nb);
    scan3_kernel<<<nb, SCAN_BS, 0, stream>>>(cnt, incl, partials, rowptr, cursor, n, ne);
    fill_kernel<<<gridE, 256, 0, stream>>>(src, dst, cursor, col, ne);

    // ---- 4 SAGE layers (gather-first; fp16 rows for the gather) ----
    to_half<<<gridC, 256, 0, stream>>>(x, Hh, n * D / 4);
    const float* cur = x;
    float* nxt = bufA;
    for (int l = 0; l < 4; l++) {
        sage_gather<<<gridG, 256, 0, stream>>>(Hh, rowptr, col, (f4*)M, n);
        sage_dense2<<<gridM, 256, 0, stream>>>((const f4*)M, (const f4*)cur,
                                               sage_Wl + (size_t)l * D * D,
                                               sage_bl + (size_t)l * D,
                                               sage_Wr + (size_t)l * D * D,
                                               (f4*)nxt, Hh, (l < 3) ? 1 : 0, n);
        cur = nxt;
        nxt = (nxt == bufA) ? bufB : bufA;
    }
    // cur == bufB

    // ---- 4 GAT layers (in-place on bufB; ht fp16 in Hh) ----
    float* gin = bufB;
    for (int l = 0; l < 4; l++) {
        gat_transform<<<gridM, 256, 0, stream>>>((const f4*)gin,
                                                 gat_W + (size_t)l * D * D,
                                                 gat_asrc + (size_t)l * D,
                                                 gat_adst + (size_t)l * D,
                                                 Hh, as_, ad_, n);
        gat_gather<<<gridG, 256, 0, stream>>>(rowptr, col, as_, ad_,
                                              Hh, gat_b + (size_t)l * D, (f4*)gin,
                                              (l < 3) ? 1 : 0, n);
    }

    // ---- projection MLP ----
    mlp_kernel<<<gridM, 256, 0, stream>>>((const f4*)gin, W1, b1, W2, b2, W3, b3, out, n);
}

// Round 14
// 864.040 us; speedup vs baseline: 1.2763x; 1.0472x over previous
//
#include <hip/hip_runtime.h>
#include <hip/hip_fp16.h>

#define D 64
#define D4 16   // D/4 float4 per row
#define PITCH 68   // fp32 LDS tile pitch (MLP)
#define HP 36      // fp16 LDS row pitch in u32 (72 halves)

typedef float4 f4;
typedef unsigned int u32;
typedef __attribute__((ext_vector_type(4))) _Float16 f16x4;
typedef __attribute__((ext_vector_type(4))) float f32x4;

__device__ __forceinline__ float leaky02(float x) { return (x >= 0.f) ? x : 0.2f * x; }

__device__ __forceinline__ f4 f4add(f4 a, f4 b) {
    return make_float4(a.x + b.x, a.y + b.y, a.z + b.z, a.w + b.w);
}
__device__ __forceinline__ f4 f4fma(float s, f4 v, f4 a) {
    return make_float4(fmaf(s, v.x, a.x), fmaf(s, v.y, a.y), fmaf(s, v.z, a.z), fmaf(s, v.w, a.w));
}
__device__ __forceinline__ f4 f4scale(f4 a, float s) {
    return make_float4(a.x * s, a.y * s, a.z * s, a.w * s);
}

__device__ __forceinline__ u32 pack2(float a, float b) {
    __half2 h = __floats2half2_rn(a, b);
    return *reinterpret_cast<u32*>(&h);
}
__device__ __forceinline__ uint2 pack4(float a, float b, float c, float d) {
    uint2 u;
    u.x = pack2(a, b);
    u.y = pack2(c, d);
    return u;
}
__device__ __forceinline__ f4 h2f4(uint2 u) {
    __half2 ha = *reinterpret_cast<__half2*>(&u.x);
    __half2 hb = *reinterpret_cast<__half2*>(&u.y);
    float2 fa = __half22float2(ha);
    float2 fb = __half22float2(hb);
    return make_float4(fa.x, fa.y, fb.x, fb.y);
}

// ---------------- CSR build ----------------

__global__ __launch_bounds__(256) void hist_kernel(const int* __restrict__ dst,
                                                   int* __restrict__ cnt, int ne) {
    int e = blockIdx.x * blockDim.x + threadIdx.x;
    if (e < ne) atomicAdd(&cnt[dst[e]], 1);
}

#define SCAN_BS 256
__global__ __launch_bounds__(SCAN_BS) void scan1_kernel(const int* __restrict__ cnt,
                                                        int* __restrict__ incl,
                                                        int* __restrict__ partials, int n) {
    __shared__ int sm[SCAN_BS];
    int g = blockIdx.x * SCAN_BS + threadIdx.x;
    int v = (g < n) ? cnt[g] : 0;
    sm[threadIdx.x] = v;
    __syncthreads();
    for (int off = 1; off < SCAN_BS; off <<= 1) {
        int t = (threadIdx.x >= off) ? sm[threadIdx.x - off] : 0;
        __syncthreads();
        sm[threadIdx.x] += t;
        __syncthreads();
    }
    if (g < n) incl[g] = sm[threadIdx.x];
    if (threadIdx.x == SCAN_BS - 1) partials[blockIdx.x] = sm[threadIdx.x];
}

__global__ __launch_bounds__(1024) void scan2_kernel(int* __restrict__ partials, int nb) {
    __shared__ int sm[1024];
    int t = threadIdx.x;
    int v = (t < nb) ? partials[t] : 0;
    sm[t] = v;
    __syncthreads();
    for (int off = 1; off < 1024; off <<= 1) {
        int x = (t >= off) ? sm[t - off] : 0;
        __syncthreads();
        sm[t] += x;
        __syncthreads();
    }
    if (t < nb) partials[t] = sm[t] - v;   // exclusive
}

__global__ __launch_bounds__(SCAN_BS) void scan3_kernel(const int* __restrict__ cnt,
                                                        const int* __restrict__ incl,
                                                        const int* __restrict__ partials,
                                                        int* __restrict__ rowptr,
                                                        int* __restrict__ cursor, int n, int ne) {
    int g = blockIdx.x * SCAN_BS + threadIdx.x;
    if (g < n) {
        int rp = incl[g] - cnt[g] + partials[blockIdx.x];
        rowptr[g] = rp;
        cursor[g] = rp;
    }
    if (g == 0) rowptr[n] = ne;
}

__global__ __launch_bounds__(256) void fill_kernel(const int* __restrict__ src,
                                                   const int* __restrict__ dst,
                                                   int* __restrict__ cursor,
                                                   int* __restrict__ col, int ne) {
    int e = blockIdx.x * blockDim.x + threadIdx.x;
    if (e < ne) {
        int pos = atomicAdd(&cursor[dst[e]], 1);
        col[pos] = src[e];
    }
}

// ---------------- fp32 -> fp16 row conversion ----------------

__global__ __launch_bounds__(256) void to_half(const float* __restrict__ in,
                                               uint2* __restrict__ out, int total4) {
    int i = blockIdx.x * 256 + threadIdx.x;
    if (i < total4) {
        f4 v = *(const f4*)&in[i * 4];
        out[i] = pack4(v.x, v.y, v.z, v.w);
    }
}

// ---------------- fp16 LDS staging for MFMA (row-major halves, pitch HP u32) ----------------

__device__ __forceinline__ void stage_h32(u32* __restrict__ T, const f4* __restrict__ G4,
                                          int t, int valid_rows) {
    int row = t >> 2, q = t & 3;
#pragma unroll
    for (int c = 0; c < 4; c++) {
        int kq = q + 4 * c;
        f4 r = make_float4(0.f, 0.f, 0.f, 0.f);
        if (row < valid_rows) r = G4[(size_t)row * 16 + kq];
        uint2 p = pack4(r.x, r.y, r.z, r.w);
        T[row * HP + kq * 2] = p.x;
        T[row * HP + kq * 2 + 1] = p.y;
    }
}

__device__ __forceinline__ f16x4 ldfrag(const u32* __restrict__ T, int row, int kidx) {
    uint2 v;
    v.x = T[row * HP + kidx * 2];
    v.y = T[row * HP + kidx * 2 + 1];
    return __builtin_bit_cast(f16x4, v);
}

// ---------------- fp32 LDS staging (MLP) ----------------

__device__ __forceinline__ void stageT(float* __restrict__ T, const f4* __restrict__ G4,
                                       int t, int valid_rows) {
    int row = t >> 2;
    int kq0 = t & 3;
#pragma unroll
    for (int c = 0; c < 4; c++) {
        int kq = kq0 + 4 * c;
        f4 r = make_float4(0.f, 0.f, 0.f, 0.f);
        if (row < valid_rows) r = G4[(size_t)row * 16 + kq];
        int k0 = kq * 4;
        T[(k0 + 0) * PITCH + row] = r.x;
        T[(k0 + 1) * PITCH + row] = r.y;
        T[(k0 + 2) * PITCH + row] = r.z;
        T[(k0 + 3) * PITCH + row] = r.w;
    }
}

#define TILE_MM(At, Wt, acc, r, c, KDIM)                                      \
    for (int k = 0; k < KDIM; k++) {                                          \
        f4 a = *(const f4*)&(At)[k * PITCH + (r) * 4];                        \
        f4 w = *(const f4*)&(Wt)[k * PITCH + (c) * 4];                        \
        acc[0][0] = fmaf(a.x, w.x, acc[0][0]);                                \
        acc[0][1] = fmaf(a.x, w.y, acc[0][1]);                                \
        acc[0][2] = fmaf(a.x, w.z, acc[0][2]);                                \
        acc[0][3] = fmaf(a.x, w.w, acc[0][3]);                                \
        acc[1][0] = fmaf(a.y, w.x, acc[1][0]);                                \
        acc[1][1] = fmaf(a.y, w.y, acc[1][1]);                                \
        acc[1][2] = fmaf(a.y, w.z, acc[1][2]);                                \
        acc[1][3] = fmaf(a.y, w.w, acc[1][3]);                                \
        acc[2][0] = fmaf(a.z, w.x, acc[2][0]);                                \
        acc[2][1] = fmaf(a.z, w.y, acc[2][1]);                                \
        acc[2][2] = fmaf(a.z, w.z, acc[2][2]);                                \
        acc[2][3] = fmaf(a.z, w.w, acc[2][3]);                                \
        acc[3][0] = fmaf(a.w, w.x, acc[3][0]);                                \
        acc[3][1] = fmaf(a.w, w.y, acc[3][1]);                                \
        acc[3][2] = fmaf(a.w, w.z, acc[3][2]);                                \
        acc[3][3] = fmaf(a.w, w.w, acc[3][3]);                                \
    }

// ---------------- SAGE gather: M[i] = mean_{j in N(i)} h[j]  (fp16 rows) ----------------

__global__ __launch_bounds__(256) void sage_gather(const uint2* __restrict__ Hh,
                                                   const int* __restrict__ rowptr,
                                                   const int* __restrict__ col,
                                                   f4* __restrict__ M, int n) {
    int lane = threadIdx.x & 63;
    int eg = lane >> 4, l16 = lane & 15;
    int wave = (blockIdx.x * 256 + threadIdx.x) >> 6;
    int nw = (gridDim.x * 256) >> 6;
    for (int node = wave; node < n; node += nw) {
        int start = rowptr[node], end = rowptr[node + 1];
        int len = end - start;
        f4 a0 = {0, 0, 0, 0}, a1 = {0, 0, 0, 0}, a2 = {0, 0, 0, 0}, a3 = {0, 0, 0, 0};
        int main16 = len & ~15;
        int o = 0;
        for (; o < main16; o += 16) {
            int i0 = start + o + eg;
            int s0 = col[i0];
            int s1 = col[i0 + 4];
            int s2 = col[i0 + 8];
            int s3 = col[i0 + 12];
            uint2 v0 = Hh[(size_t)s0 * D4 + l16];
            uint2 v1 = Hh[(size_t)s1 * D4 + l16];
            uint2 v2 = Hh[(size_t)s2 * D4 + l16];
            uint2 v3 = Hh[(size_t)s3 * D4 + l16];
            a0 = f4add(a0, h2f4(v0)); a1 = f4add(a1, h2f4(v1));
            a2 = f4add(a2, h2f4(v2)); a3 = f4add(a3, h2f4(v3));
        }
        int rem = len - o;
        if (rem > 0) {
            int i0 = start + o;
            if (eg < rem)      a0 = f4add(a0, h2f4(Hh[(size_t)col[i0 + eg] * D4 + l16]));
            if (eg + 4 < rem)  a1 = f4add(a1, h2f4(Hh[(size_t)col[i0 + 4 + eg] * D4 + l16]));
            if (eg + 8 < rem)  a2 = f4add(a2, h2f4(Hh[(size_t)col[i0 + 8 + eg] * D4 + l16]));
            if (eg + 12 < rem) a3 = f4add(a3, h2f4(Hh[(size_t)col[i0 + 12 + eg] * D4 + l16]));
        }
        f4 a = f4add(f4add(a0, a1), f4add(a2, a3));
        a.x += __shfl_xor(a.x, 16); a.y += __shfl_xor(a.y, 16);
        a.z += __shfl_xor(a.z, 16); a.w += __shfl_xor(a.w, 16);
        a.x += __shfl_xor(a.x, 32); a.y += __shfl_xor(a.y, 32);
        a.z += __shfl_xor(a.z, 32); a.w += __shfl_xor(a.w, 32);
        if (eg == 0) {
            float invd = 1.f / fmaxf((float)len, 1.f);
            M[(size_t)node * D4 + l16] =
                make_float4(a.x * invd, a.y * invd, a.z * invd, a.w * invd);
        }
    }
}

// ---------------- SAGE dense (MFMA): out = relu?(M@Wl.T + h@Wr.T + bl), + fp16 copy ----------------
// 4 waves; wave w owns rows w*16..w*16+15; 4 C-frags (16x16) over 64 cols.

__global__ __launch_bounds__(256) void sage_dense_mfma(const f4* __restrict__ M4,
                                                       const f4* __restrict__ h4,
                                                       const float* __restrict__ Wl,
                                                       const float* __restrict__ bl,
                                                       const float* __restrict__ Wr,
                                                       float* __restrict__ outf,
                                                       u32* __restrict__ outh32,
                                                       int relu_flag, int n) {
    __shared__ __align__(16) u32 Ah[64 * HP];
    __shared__ __align__(16) u32 Bh[64 * HP];
    int t = threadIdx.x;
    int nb = blockIdx.x * 64;
    int w = t >> 6, l = t & 63;
    int lr = l & 15, g = l >> 4;
    f32x4 acc[4] = {{0, 0, 0, 0}, {0, 0, 0, 0}, {0, 0, 0, 0}, {0, 0, 0, 0}};
    stage_h32(Ah, M4 + (size_t)nb * 16, t, n - nb);
    stage_h32(Bh, (const f4*)Wl, t, 64);
    __syncthreads();
#pragma unroll
    for (int kb = 0; kb < 4; kb++) {
        f16x4 af = ldfrag(Ah, w * 16 + lr, kb * 4 + g);
#pragma unroll
        for (int ob = 0; ob < 4; ob++) {
            f16x4 bf = ldfrag(Bh, ob * 16 + lr, kb * 4 + g);
            acc[ob] = __builtin_amdgcn_mfma_f32_16x16x16f16(af, bf, acc[ob], 0, 0, 0);
        }
    }
    __syncthreads();
    stage_h32(Ah, h4 + (size_t)nb * 16, t, n - nb);
    stage_h32(Bh, (const f4*)Wr, t, 64);
    __syncthreads();
#pragma unroll
    for (int kb = 0; kb < 4; kb++) {
        f16x4 af = ldfrag(Ah, w * 16 + lr, kb * 4 + g);
#pragma unroll
        for (int ob = 0; ob < 4; ob++) {
            f16x4 bf = ldfrag(Bh, ob * 16 + lr, kb * 4 + g);
            acc[ob] = __builtin_amdgcn_mfma_f32_16x16x16f16(af, bf, acc[ob], 0, 0, 0);
        }
    }
#pragma unroll
    for (int ob = 0; ob < 4; ob++) {
        int colx = ob * 16 + lr;
        float bv = bl[colx];
#pragma unroll
        for (int j = 0; j < 4; j++) {
            int row = w * 16 + 4 * g + j;
            int node = nb + row;
            float v = acc[ob][j] + bv;
            if (relu_flag) v = fmaxf(v, 0.f);
            float vup = __shfl_down(v, 1);
            if (node < n) {
                outf[(size_t)node * 64 + colx] = v;
                if ((lr & 1) == 0) outh32[(size_t)node * 32 + (colx >> 1)] = pack2(v, vup);
            }
        }
    }
}

// ---------------- GAT dense (MFMA): ht(fp16) = h@W.T ; as = ht.a_src ; ad = ht.a_dst ----------------

__global__ __launch_bounds__(256) void gat_transform_mfma(const f4* __restrict__ h4,
                                                          const float* __restrict__ W,
                                                          const float* __restrict__ a_src,
                                                          const float* __restrict__ a_dst,
                                                          u32* __restrict__ hth32,
                                                          float* __restrict__ as_,
                                                          float* __restrict__ ad_, int n) {
    __shared__ __align__(16) u32 Ah[64 * HP];
    __shared__ __align__(16) u32 Bh[64 * HP];
    int t = threadIdx.x;
    int nb = blockIdx.x * 64;
    int w = t >> 6, l = t & 63;
    int lr = l & 15, g = l >> 4;
    f32x4 acc[4] = {{0, 0, 0, 0}, {0, 0, 0, 0}, {0, 0, 0, 0}, {0, 0, 0, 0}};
    stage_h32(Ah, h4 + (size_t)nb * 16, t, n - nb);
    stage_h32(Bh, (const f4*)W, t, 64);
    __syncthreads();
#pragma unroll
    for (int kb = 0; kb < 4; kb++) {
        f16x4 af = ldfrag(Ah, w * 16 + lr, kb * 4 + g);
#pragma unroll
        for (int ob = 0; ob < 4; ob++) {
            f16x4 bf = ldfrag(Bh, ob * 16 + lr, kb * 4 + g);
            acc[ob] = __builtin_amdgcn_mfma_f32_16x16x16f16(af, bf, acc[ob], 0, 0, 0);
        }
    }
    float asv[4], adv[4];
#pragma unroll
    for (int ob = 0; ob < 4; ob++) {
        asv[ob] = a_src[ob * 16 + lr];
        adv[ob] = a_dst[ob * 16 + lr];
    }
#pragma unroll
    for (int j = 0; j < 4; j++) {
        int row = w * 16 + 4 * g + j;
        int node = nb + row;
        float ps = 0.f, pd = 0.f;
#pragma unroll
        for (int ob = 0; ob < 4; ob++) {
            ps = fmaf(acc[ob][j], asv[ob], ps);
            pd = fmaf(acc[ob][j], adv[ob], pd);
        }
#pragma unroll
        for (int off = 1; off < 16; off <<= 1) {
            ps += __shfl_xor(ps, off);
            pd += __shfl_xor(pd, off);
        }
        if (lr == 0 && node < n) {
            as_[node] = ps;
            ad_[node] = pd;
        }
#pragma unroll
        for (int ob = 0; ob < 4; ob++) {
            int colx = ob * 16 + lr;
            float v = acc[ob][j];
            float vup = __shfl_down(v, 1);
            if (node < n && (lr & 1) == 0)
                hth32[(size_t)node * 32 + (colx >> 1)] = pack2(v, vup);
        }
    }
}

// ---------------- GAT gather: one wave per node, exact online softmax, fp16 rows ----------------

__global__ __launch_bounds__(256) void gat_gather(const int* __restrict__ rowptr,
                                                  const int* __restrict__ col,
                                                  const float* __restrict__ as_,
                                                  const float* __restrict__ ad_,
                                                  const uint2* __restrict__ Hh,
                                                  const float* __restrict__ b,
                                                  f4* __restrict__ out,
                                                  int relu_flag, int n) {
    int lane = threadIdx.x & 63;
    int eg = lane >> 4, l16 = lane & 15;
    int wave = (blockIdx.x * 256 + threadIdx.x) >> 6;
    int nw = (gridDim.x * 256) >> 6;
    const f4* b4 = (const f4*)b;
    for (int node = wave; node < n; node += nw) {
        int start = rowptr[node], end = rowptr[node + 1];
        int len = end - start;
        float ad_n = ad_[node];
        float e_self = leaky02(as_[node] + ad_n);
        float m = e_self;
        float zp = (eg == 0) ? 1.f : 0.f;
        f4 acc = {0, 0, 0, 0};
        if (eg == 0) acc = h2f4(Hh[(size_t)node * D4 + l16]);
        int main16 = len & ~15;
        int o = 0;
        for (; o < main16; o += 16) {
            int i0 = start + o + eg;
            int s0 = col[i0];
            int s1 = col[i0 + 4];
            int s2 = col[i0 + 8];
            int s3 = col[i0 + 12];
            uint2 v0 = Hh[(size_t)s0 * D4 + l16];
            uint2 v1 = Hh[(size_t)s1 * D4 + l16];
            uint2 v2 = Hh[(size_t)s2 * D4 + l16];
            uint2 v3 = Hh[(size_t)s3 * D4 + l16];
            float e0 = leaky02(as_[s0] + ad_n);
            float e1 = leaky02(as_[s1] + ad_n);
            float e2 = leaky02(as_[s2] + ad_n);
            float e3 = leaky02(as_[s3] + ad_n);
            float em = fmaxf(fmaxf(e0, e1), fmaxf(e2, e3));
            em = fmaxf(em, __shfl_xor(em, 16));
            em = fmaxf(em, __shfl_xor(em, 32));
            if (em > m) {
                float sc = __expf(m - em);
                zp *= sc;
                acc = f4scale(acc, sc);
                m = em;
            }
            float p0 = __expf(e0 - m);
            float p1 = __expf(e1 - m);
            float p2 = __expf(e2 - m);
            float p3 = __expf(e3 - m);
            zp += (p0 + p1) + (p2 + p3);
            acc = f4fma(p0, h2f4(v0), acc);
            acc = f4fma(p1, h2f4(v1), acc);
            acc = f4fma(p2, h2f4(v2), acc);
            acc = f4fma(p3, h2f4(v3), acc);
        }
        int rem = len - o;
        if (rem > 0) {
            int i0 = start + o;
            bool v0b = eg < rem, v1b = eg + 4 < rem, v2b = eg + 8 < rem, v3b = eg + 12 < rem;
            int s0 = v0b ? col[i0 + eg] : 0;
            int s1 = v1b ? col[i0 + 4 + eg] : 0;
            int s2 = v2b ? col[i0 + 8 + eg] : 0;
            int s3 = v3b ? col[i0 + 12 + eg] : 0;
            float e0 = v0b ? leaky02(as_[s0] + ad_n) : -3.4e38f;
            float e1 = v1b ? leaky02(as_[s1] + ad_n) : -3.4e38f;
            float e2 = v2b ? leaky02(as_[s2] + ad_n) : -3.4e38f;
            float e3 = v3b ? leaky02(as_[s3] + ad_n) : -3.4e38f;
            float em = fmaxf(fmaxf(e0, e1), fmaxf(e2, e3));
            em = fmaxf(em, __shfl_xor(em, 16));
            em = fmaxf(em, __shfl_xor(em, 32));
            if (em > m) {
                float sc = __expf(m - em);
                zp *= sc;
                acc = f4scale(acc, sc);
                m = em;
            }
            float p0 = v0b ? __expf(e0 - m) : 0.f;
            float p1 = v1b ? __expf(e1 - m) : 0.f;
            float p2 = v2b ? __expf(e2 - m) : 0.f;
            float p3 = v3b ? __expf(e3 - m) : 0.f;
            zp += (p0 + p1) + (p2 + p3);
            if (v0b) acc = f4fma(p0, h2f4(Hh[(size_t)s0 * D4 + l16]), acc);
            if (v1b) acc = f4fma(p1, h2f4(Hh[(size_t)s1 * D4 + l16]), acc);
            if (v2b) acc = f4fma(p2, h2f4(Hh[(size_t)s2 * D4 + l16]), acc);
            if (v3b) acc = f4fma(p3, h2f4(Hh[(size_t)s3 * D4 + l16]), acc);
        }
        float z = zp;
        z += __shfl_xor(z, 16);
        z += __shfl_xor(z, 32);
        acc.x += __shfl_xor(acc.x, 16); acc.y += __shfl_xor(acc.y, 16);
        acc.z += __shfl_xor(acc.z, 16); acc.w += __shfl_xor(acc.w, 16);
        acc.x += __shfl_xor(acc.x, 32); acc.y += __shfl_xor(acc.y, 32);
        acc.z += __shfl_xor(acc.z, 32); acc.w += __shfl_xor(acc.w, 32);
        if (eg == 0) {
            float rz = 1.f / z;
            f4 bb = b4[l16];
            f4 o4 = make_float4(fmaf(acc.x, rz, bb.x), fmaf(acc.y, rz, bb.y),
                                fmaf(acc.z, rz, bb.z), fmaf(acc.w, rz, bb.w));
            if (relu_flag) {
                o4.x = fmaxf(o4.x, 0.f); o4.y = fmaxf(o4.y, 0.f);
                o4.z = fmaxf(o4.z, 0.f); o4.w = fmaxf(o4.w, 0.f);
            }
            out[(size_t)node * D4 + l16] = o4;
        }
    }
}

// ---------------- MLP: tiled 3-layer chain in one kernel (fp32) ----------------

__global__ __launch_bounds__(256) void mlp_kernel(const f4* __restrict__ h4,
                                                  const float* __restrict__ W1,
                                                  const float* __restrict__ b1,
                                                  const float* __restrict__ W2,
                                                  const float* __restrict__ b2,
                                                  const float* __restrict__ W3,
                                                  const float* __restrict__ b3,
                                                  float* __restrict__ out, int n) {
    __shared__ float At[64 * PITCH];
    __shared__ float Wt[64 * PITCH];
    __shared__ float V2[32 * PITCH];
    int t = threadIdx.x;
    int nb = blockIdx.x * 64;
    int r = t >> 4, c = t & 15;
    stageT(At, h4 + (size_t)nb * 16, t, n - nb);
    stageT(Wt, (const f4*)W1, t, 64);
    __syncthreads();
    float a1v[4][4] = {{0.f}};
    TILE_MM(At, Wt, a1v, r, c, 64)
    f4 b1v = ((const f4*)b1)[c];
    __syncthreads();
    {
        float bb[4] = {b1v.x, b1v.y, b1v.z, b1v.w};
#pragma unroll
        for (int i = 0; i < 4; i++)
#pragma unroll
            for (int j = 0; j < 4; j++)
                At[(c * 4 + j) * PITCH + r * 4 + i] = fmaxf(a1v[i][j] + bb[j], 0.f);
    }
    stageT(Wt, (const f4*)W2, t, 32);
    __syncthreads();
    float a2v[4][2] = {{0.f}};
    for (int k = 0; k < 64; k++) {
        f4 a = *(const f4*)&At[k * PITCH + r * 4];
        float w0 = Wt[k * PITCH + c * 2];
        float w1 = Wt[k * PITCH + c * 2 + 1];
        a2v[0][0] = fmaf(a.x, w0, a2v[0][0]); a2v[0][1] = fmaf(a.x, w1, a2v[0][1]);
        a2v[1][0] = fmaf(a.y, w0, a2v[1][0]); a2v[1][1] = fmaf(a.y, w1, a2v[1][1]);
        a2v[2][0] = fmaf(a.z, w0, a2v[2][0]); a2v[2][1] = fmaf(a.z, w1, a2v[2][1]);
        a2v[3][0] = fmaf(a.w, w0, a2v[3][0]); a2v[3][1] = fmaf(a.w, w1, a2v[3][1]);
    }
    float b20 = b2[c * 2], b21 = b2[c * 2 + 1];
    __syncthreads();
#pragma unroll
    for (int i = 0; i < 4; i++) {
        V2[(c * 2 + 0) * PITCH + r * 4 + i] = fmaxf(a2v[i][0] + b20, 0.f);
        V2[(c * 2 + 1) * PITCH + r * 4 + i] = fmaxf(a2v[i][1] + b21, 0.f);
    }
    if (t < 128) {
        int row = t >> 3, kq = t & 7;
        f4 w = ((const f4*)W3)[row * 8 + kq];
        int k0 = kq * 4;
        Wt[(k0 + 0) * PITCH + row] = w.x;
        Wt[(k0 + 1) * PITCH + row] = w.y;
        Wt[(k0 + 2) * PITCH + row] = w.z;
        Wt[(k0 + 3) * PITCH + row] = w.w;
    }
    __syncthreads();
    float a3v[4] = {0.f, 0.f, 0.f, 0.f};
    for (int k = 0; k < 32; k++) {
        f4 a = *(const f4*)&V2[k * PITCH + r * 4];
        float w = Wt[k * PITCH + c];
        a3v[0] = fmaf(a.x, w, a3v[0]);
        a3v[1] = fmaf(a.y, w, a3v[1]);
        a3v[2] = fmaf(a.z, w, a3v[2]);
        a3v[3] = fmaf(a.w, w, a3v[3]);
    }
    float b3v = b3[c];
#pragma unroll
    for (int i = 0; i < 4; i++) {
        int node = nb + r * 4 + i;
        if (node < n) out[(size_t)node * 16 + c] = a3v[i] + b3v;
    }
}

// ---------------- launch ----------------

extern "C" void kernel_launch(void* const* d_in, const int* in_sizes, int n_in,
                              void* d_out, int out_size, void* d_ws, size_t ws_size,
                              hipStream_t stream) {
    const int n  = in_sizes[0] / D;      // 100000
    const int ne = in_sizes[1] / 2;      // 1600000

    const float* x        = (const float*)d_in[0];
    const int*   ei       = (const int*)d_in[1];
    const int*   src      = ei;
    const int*   dst      = ei + ne;
    const float* sage_Wl  = (const float*)d_in[2];
    const float* sage_bl  = (const float*)d_in[3];
    const float* sage_Wr  = (const float*)d_in[4];
    const float* gat_W    = (const float*)d_in[5];
    const float* gat_asrc = (const float*)d_in[6];
    const float* gat_adst = (const float*)d_in[7];
    const float* gat_b    = (const float*)d_in[8];
    const float* W1 = (const float*)d_in[9];
    const float* b1 = (const float*)d_in[10];
    const float* W2 = (const float*)d_in[11];
    const float* b2 = (const float*)d_in[12];
    const float* W3 = (const float*)d_in[13];
    const float* b3 = (const float*)d_in[14];
    float* out = (float*)d_out;

    // workspace layout (4B units, all offsets 16B-aligned)
    int*   cnt      = (int*)d_ws;                    // n
    int*   incl     = cnt + n;                       // n
    int*   rowptr   = incl + n;                      // n+4
    int*   cursor   = rowptr + n + 4;                // n
    int*   partials = cursor + n;                    // 1024
    int*   col      = partials + 1024;               // ne
    float* as_      = (float*)(col + ne);            // n
    float* ad_      = as_ + n;                       // n
    float* M        = ad_ + n;                       // n*D fp32 (sage mean)
    float* bufA     = M + (size_t)n * D;             // n*D
    float* bufB     = bufA + (size_t)n * D;          // n*D
    uint2* Hh       = (uint2*)(bufB + (size_t)n * D); // n*16 uint2 = n*D halves

    const int gridE  = (ne + 255) / 256;
    const int nb     = (n + SCAN_BS - 1) / SCAN_BS;
    const int gridG  = 4096;
    const int gridM  = (n + 63) / 64;
    const int gridC  = (n * D / 4 + 255) / 256;

    // ---- CSR build ----
    hipMemsetAsync(cnt, 0, (size_t)n * 4, stream);
    hist_kernel<<<gridE, 256, 0, stream>>>(dst, cnt, ne);
    scan1_kernel<<<nb, SCAN_BS, 0, stream>>>(cnt, incl, partials, n);
    scan2_kernel<<<1, 1024, 0, stream>>>(partials, nb);
    scan3_kernel<<<nb, SCAN_BS, 0, stream>>>(cnt, incl, partials, rowptr, cursor, n, ne);
    fill_kernel<<<gridE, 256, 0, stream>>>(src, dst, cursor, col, ne);

    // ---- 4 SAGE layers (gather-first; fp16 rows for gather, MFMA dense) ----
    to_half<<<gridC, 256, 0, stream>>>(x, Hh, n * D / 4);
    const float* cur = x;
    float* nxt = bufA;
    for (int l = 0; l < 4; l++) {
        sage_gather<<<gridG, 256, 0, stream>>>(Hh, rowptr, col, (f4*)M, n);
        sage_dense_mfma<<<gridM, 256, 0, stream>>>((const f4*)M, (const f4*)cur,
                                                   sage_Wl + (size_t)l * D * D,
                                                   sage_bl + (size_t)l * D,
                                                   sage_Wr + (size_t)l * D * D,
                                                   nxt, (u32*)Hh, (l < 3) ? 1 : 0, n);
        cur = nxt;
        nxt = (nxt == bufA) ? bufB : bufA;
    }
    // cur == bufB

    // ---- 4 GAT layers (in-place on bufB; ht fp16 in Hh, MFMA transform) ----
    float* gin = bufB;
    for (int l = 0; l < 4; l++) {
        gat_transform_mfma<<<gridM, 256, 0, stream>>>((const f4*)gin,
                                                      gat_W + (size_t)l * D * D,
                                                      gat_asrc + (size_t)l * D,
                                                      gat_adst + (size_t)l * D,
                                                      (u32*)Hh, as_, ad_, n);
        gat_gather<<<gridG, 256, 0, stream>>>(rowptr, col, as_, ad_,
                                              Hh, gat_b + (size_t)l * D, (f4*)gin,
                                              (l < 3) ? 1 : 0, n);
    }

    // ---- projection MLP ----
    mlp_kernel<<<gridM, 256, 0, stream>>>((const f4*)gin, W1, b1, W2, b2, W3, b3, out, n);
}